// Round 1
// baseline (168.633 us; speedup 1.0000x reference)
//
#include <hip/hip_runtime.h>
#include <stdint.h>

// Problem constants (GINConv1d_74002286510472): B=4, N=8192, K=16, C_IN=C_OUT=128
#define BATCH   4
#define NNODE   8192
#define KNBR    16
#define CIN     128
#define COUT    128
#define MB      64          // rows (nodes) per block
#define THREADS 256
#define HS_STRIDE 136       // shorts per h_s row: 128 + 8 pad -> 272B stride, uniform bank spread

typedef __attribute__((ext_vector_type(8))) short short8;   // 8 bf16 = 4 VGPRs (MFMA A/B frag)
typedef __attribute__((ext_vector_type(4))) float f32x4;

__device__ __forceinline__ short bf16_rne(float f) {
    union { float f; uint32_t u; } v; v.f = f;
    return (short)((v.u + 0x7FFFu + ((v.u >> 16) & 1u)) >> 16);  // round-to-nearest-even
}

extern "C" __global__ __launch_bounds__(THREADS, 4)
void gin_fused(const float* __restrict__ x,      // [B,N,CIN] fp32
               const int*   __restrict__ eidx,   // [2,B,N,K] int32; plane 0 = source idx
               const float* __restrict__ W,      // [COUT,CIN] fp32
               const float* __restrict__ bias,   // [COUT] fp32
               const float* __restrict__ epsp,   // [1] fp32
               float*       __restrict__ out)    // [B,N,COUT] fp32
{
    __shared__ __align__(16) short h_s[MB * HS_STRIDE];

    const int tid  = threadIdx.x;
    const int row0 = blockIdx.x * MB;        // global row base (b*N + n)
    const int b    = row0 / NNODE;           // MB divides NNODE -> whole block same batch
    const int n0   = row0 - b * NNODE;

    const float eps1 = 1.0f + epsp[0];

    // ---------------- Phase A: gather + sum + eps-residual -> h_s (bf16) -------------
    {
        const int r  = tid >> 2;             // row within block, 0..63
        const int q  = tid & 3;              // channel quarter, 32 ch each
        const int n  = n0 + r;
        const int c0 = q * 32;
        const float* xb = x + (size_t)b * NNODE * CIN;
        const int*   ip = eidx + ((size_t)b * NNODE + n) * KNBR;   // plane 0

        float acc[32];
        const float* xs = xb + (size_t)n * CIN + c0;
        #pragma unroll
        for (int i = 0; i < 8; ++i) {
            f32x4 v = *(const f32x4*)(xs + i * 4);
            acc[i*4+0] = eps1 * v[0];
            acc[i*4+1] = eps1 * v[1];
            acc[i*4+2] = eps1 * v[2];
            acc[i*4+3] = eps1 * v[3];
        }
        #pragma unroll
        for (int p = 0; p < 4; ++p) {
            int4 jv = *(const int4*)(ip + p * 4);
            int js[4] = { jv.x, jv.y, jv.z, jv.w };
            #pragma unroll
            for (int kk = 0; kk < 4; ++kk) {
                const float* xn = xb + (size_t)js[kk] * CIN + c0;
                #pragma unroll
                for (int i = 0; i < 8; ++i) {
                    f32x4 v = *(const f32x4*)(xn + i * 4);
                    acc[i*4+0] += v[0];
                    acc[i*4+1] += v[1];
                    acc[i*4+2] += v[2];
                    acc[i*4+3] += v[3];
                }
            }
        }
        short* hp = h_s + r * HS_STRIDE + c0;
        #pragma unroll
        for (int p = 0; p < 4; ++p) {
            short8 s;
            #pragma unroll
            for (int e = 0; e < 8; ++e) s[e] = bf16_rne(acc[p*8+e]);
            *(short8*)(hp + p * 8) = s;   // 16B ds_write, uniform bank-group spread
        }
    }

    // ---------------- W -> bf16 B-fragments in registers (per-wave 32-out slice) -----
    const int wave = tid >> 6;
    const int lane = tid & 63;
    const int l16  = lane & 15;
    const int lq   = lane >> 4;          // quad 0..3

    short8 bfrag[2][4];                  // [o_tile][kb]: B[k][n]=W[o][c], n=l16, k=lq*8+j
    #pragma unroll
    for (int t = 0; t < 2; ++t) {
        const float* wp = W + (size_t)(wave * 32 + t * 16 + l16) * CIN;
        #pragma unroll
        for (int kb = 0; kb < 4; ++kb) {
            const float* wq = wp + kb * 32 + lq * 8;
            f32x4 f0 = *(const f32x4*)(wq);
            f32x4 f1 = *(const f32x4*)(wq + 4);
            short8 s;
            s[0]=bf16_rne(f0[0]); s[1]=bf16_rne(f0[1]); s[2]=bf16_rne(f0[2]); s[3]=bf16_rne(f0[3]);
            s[4]=bf16_rne(f1[0]); s[5]=bf16_rne(f1[1]); s[6]=bf16_rne(f1[2]); s[7]=bf16_rne(f1[3]);
            bfrag[t][kb] = s;
        }
    }

    const float bias0 = bias[wave * 32 + l16];
    const float bias1 = bias[wave * 32 + 16 + l16];

    __syncthreads();

    // ---------------- Phase B: MFMA GEMM + bias + ReLU -------------------------------
    float* outb = out + (size_t)row0 * COUT;
    #pragma unroll
    for (int rt = 0; rt < 4; ++rt) {
        // A frag: m = l16 (row within 16-tile), k = lq*8 + j  -> 16B ds_read_b128
        const short* ap = h_s + (rt * 16 + l16) * HS_STRIDE + lq * 8;
        short8 afrag[4];
        #pragma unroll
        for (int kb = 0; kb < 4; ++kb)
            afrag[kb] = *(const short8*)(ap + kb * 32);

        #pragma unroll
        for (int t = 0; t < 2; ++t) {
            f32x4 acc = { 0.f, 0.f, 0.f, 0.f };
            #pragma unroll
            for (int kb = 0; kb < 4; ++kb)
                acc = __builtin_amdgcn_mfma_f32_16x16x32_bf16(afrag[kb], bfrag[t][kb], acc, 0, 0, 0);

            const float bv  = t ? bias1 : bias0;
            const int   col = wave * 32 + t * 16 + l16;
            #pragma unroll
            for (int i = 0; i < 4; ++i) {
                const int row = rt * 16 + lq * 4 + i;   // C/D: row = quad*4 + reg
                float v = acc[i] + bv;
                outb[(size_t)row * COUT + col] = v > 0.f ? v : 0.f;
            }
        }
    }
}

extern "C" void kernel_launch(void* const* d_in, const int* in_sizes, int n_in,
                              void* d_out, int out_size, void* d_ws, size_t ws_size,
                              hipStream_t stream) {
    const float* x    = (const float*)d_in[0];
    const int*   eidx = (const int*)d_in[1];
    const float* W    = (const float*)d_in[2];
    const float* bias = (const float*)d_in[3];
    const float* eps  = (const float*)d_in[4];
    float*       out  = (float*)d_out;

    dim3 grid((BATCH * NNODE) / MB);   // 512 blocks
    gin_fused<<<grid, THREADS, 0, stream>>>(x, eidx, W, bias, eps, out);
}

// Round 2
// 95.368 us; speedup vs baseline: 1.7682x; 1.7682x over previous
//
#include <hip/hip_runtime.h>
#include <stdint.h>

// GINConv1d: B=4, N=8192, K=16, C_IN=C_OUT=128
#define BATCH   4
#define NNODE   8192
#define KNBR    16
#define CIN     128
#define COUT    128
#define MB      32          // rows (nodes) per block -> 1024 blocks
#define THREADS 256
#define HS_STRIDE 136       // shorts per h_s row: 128 + 8 pad -> 272B stride, uniform bank spread

typedef __attribute__((ext_vector_type(8))) short short8;   // 8 bf16 (MFMA A/B frag)
typedef __attribute__((ext_vector_type(4))) float f32x4;

__device__ __forceinline__ short bf16_rne(float f) {
    union { float f; uint32_t u; } v; v.f = f;
    return (short)((v.u + 0x7FFFu + ((v.u >> 16) & 1u)) >> 16);  // round-to-nearest-even
}
__device__ __forceinline__ float bf16_f32(short s) {
    union { uint32_t u; float f; } v; v.u = ((uint32_t)(uint16_t)s) << 16;
    return v.f;
}

// ---------------- prepass: x fp32 -> bf16 in workspace -----------------------------
__global__ __launch_bounds__(256)
void cvt_bf16(const float* __restrict__ x, ushort* __restrict__ xb) {
    const int gid = blockIdx.x * 256 + threadIdx.x;       // 8 elements per thread
    const f32x4* xp = (const f32x4*)x + (size_t)gid * 2;
    f32x4 a = xp[0], c = xp[1];
    short8 s;
    s[0]=bf16_rne(a[0]); s[1]=bf16_rne(a[1]); s[2]=bf16_rne(a[2]); s[3]=bf16_rne(a[3]);
    s[4]=bf16_rne(c[0]); s[5]=bf16_rne(c[1]); s[6]=bf16_rne(c[2]); s[7]=bf16_rne(c[3]);
    ((short8*)xb)[gid] = s;
}

// ---------------- fused gather + eps-residual + MFMA GEMM + bias + ReLU ------------
template<bool USEBF>
__global__ __launch_bounds__(THREADS, 4)
void gin_fused(const float*  __restrict__ x,      // [B,N,CIN] fp32
               const ushort* __restrict__ xb,     // [B,N,CIN] bf16 (if USEBF)
               const int*    __restrict__ eidx,   // [2,B,N,K] int32; plane 0 = source idx
               const float*  __restrict__ W,      // [COUT,CIN] fp32
               const float*  __restrict__ bias,   // [COUT] fp32
               const float*  __restrict__ epsp,   // [1] fp32
               float*        __restrict__ out)    // [B,N,COUT] fp32
{
    __shared__ __align__(16) short h_s[MB * HS_STRIDE];

    const int tid = threadIdx.x;
    // XCD-locality swizzle: blockIdx -> XCD is round-robin (i & 7) on MI355X.
    // Pin batch b to XCDs {2b, 2b+1} so each XCD's gather set = one batch (2 MiB bf16) -> L2-resident.
    const int i   = blockIdx.x;            // 0..1023
    const int xcd = i & 7;
    const int sub = i >> 3;                // 0..127
    const int b   = xcd >> 1;              // batch 0..3
    const int wbi = ((xcd & 1) << 7) | sub;// 0..255 within batch
    const int n0  = wbi * MB;
    const int row0 = b * NNODE + n0;

    const float eps1 = 1.0f + epsp[0];

    // ---------------- Phase A: gather + sum -> h_s (bf16) --------------------------
    {
        const int r  = tid >> 3;           // row within block, 0..31
        const int q  = tid & 7;            // channel slice, 16 ch each
        const int n  = n0 + r;
        const int c0 = q * 16;
        const int* ip = eidx + ((size_t)b * NNODE + n) * KNBR;   // plane 0

        float acc[16];
        int js[16];
        #pragma unroll
        for (int p = 0; p < 4; ++p) {
            int4 jv = *(const int4*)(ip + p * 4);
            js[p*4+0]=jv.x; js[p*4+1]=jv.y; js[p*4+2]=jv.z; js[p*4+3]=jv.w;
        }

        if constexpr (USEBF) {
            const ushort* xbb = xb + (size_t)b * NNODE * CIN;
            const ushort* xs  = xbb + (size_t)n * CIN + c0;
            short8 s0 = *(const short8*)xs, s1 = *(const short8*)(xs + 8);
            #pragma unroll
            for (int e = 0; e < 8; ++e) {
                acc[e]     = eps1 * bf16_f32(s0[e]);
                acc[8 + e] = eps1 * bf16_f32(s1[e]);
            }
            #pragma unroll
            for (int k = 0; k < KNBR; ++k) {
                const ushort* xn = xbb + (size_t)js[k] * CIN + c0;
                short8 t0 = *(const short8*)xn, t1 = *(const short8*)(xn + 8);
                #pragma unroll
                for (int e = 0; e < 8; ++e) {
                    acc[e]     += bf16_f32(t0[e]);
                    acc[8 + e] += bf16_f32(t1[e]);
                }
            }
        } else {
            const float* xbb = x + (size_t)b * NNODE * CIN;
            const float* xs  = xbb + (size_t)n * CIN + c0;
            #pragma unroll
            for (int p = 0; p < 4; ++p) {
                f32x4 v = *(const f32x4*)(xs + p * 4);
                acc[p*4+0]=eps1*v[0]; acc[p*4+1]=eps1*v[1]; acc[p*4+2]=eps1*v[2]; acc[p*4+3]=eps1*v[3];
            }
            #pragma unroll
            for (int k = 0; k < KNBR; ++k) {
                const float* xn = xbb + (size_t)js[k] * CIN + c0;
                #pragma unroll
                for (int p = 0; p < 4; ++p) {
                    f32x4 v = *(const f32x4*)(xn + p * 4);
                    acc[p*4+0]+=v[0]; acc[p*4+1]+=v[1]; acc[p*4+2]+=v[2]; acc[p*4+3]+=v[3];
                }
            }
        }

        short* hp = h_s + r * HS_STRIDE + c0;
        #pragma unroll
        for (int p = 0; p < 2; ++p) {
            short8 s;
            #pragma unroll
            for (int e = 0; e < 8; ++e) s[e] = bf16_rne(acc[p*8+e]);
            *(short8*)(hp + p * 8) = s;
        }
    }

    // ---------------- W -> bf16 B-fragments in registers (per-wave 32-out slice) ---
    const int wave = tid >> 6;
    const int lane = tid & 63;
    const int l16  = lane & 15;
    const int lq   = lane >> 4;            // quad 0..3

    short8 bfrag[2][4];                    // [o_tile][kb]: B[k][n]=W[o][c], n=l16, k=lq*8+j
    #pragma unroll
    for (int t = 0; t < 2; ++t) {
        const float* wp = W + (size_t)(wave * 32 + t * 16 + l16) * CIN;
        #pragma unroll
        for (int kb = 0; kb < 4; ++kb) {
            const float* wq = wp + kb * 32 + lq * 8;
            f32x4 f0 = *(const f32x4*)(wq);
            f32x4 f1 = *(const f32x4*)(wq + 4);
            short8 s;
            s[0]=bf16_rne(f0[0]); s[1]=bf16_rne(f0[1]); s[2]=bf16_rne(f0[2]); s[3]=bf16_rne(f0[3]);
            s[4]=bf16_rne(f1[0]); s[5]=bf16_rne(f1[1]); s[6]=bf16_rne(f1[2]); s[7]=bf16_rne(f1[3]);
            bfrag[t][kb] = s;
        }
    }
    const float bias0 = bias[wave * 32 + l16];
    const float bias1 = bias[wave * 32 + 16 + l16];

    __syncthreads();

    // ---------------- Phase B: MFMA GEMM + bias + ReLU -----------------------------
    float* outb = out + (size_t)row0 * COUT;
    #pragma unroll
    for (int rt = 0; rt < MB / 16; ++rt) {
        const short* ap = h_s + (rt * 16 + l16) * HS_STRIDE + lq * 8;
        short8 afrag[4];
        #pragma unroll
        for (int kb = 0; kb < 4; ++kb)
            afrag[kb] = *(const short8*)(ap + kb * 32);

        #pragma unroll
        for (int t = 0; t < 2; ++t) {
            f32x4 acc = { 0.f, 0.f, 0.f, 0.f };
            #pragma unroll
            for (int kb = 0; kb < 4; ++kb)
                acc = __builtin_amdgcn_mfma_f32_16x16x32_bf16(afrag[kb], bfrag[t][kb], acc, 0, 0, 0);

            const float bv  = t ? bias1 : bias0;
            const int   col = wave * 32 + t * 16 + l16;
            #pragma unroll
            for (int ii = 0; ii < 4; ++ii) {
                const int row = rt * 16 + lq * 4 + ii;   // C/D: row = quad*4 + reg
                float v = acc[ii] + bv;
                outb[(size_t)row * COUT + col] = v > 0.f ? v : 0.f;
            }
        }
    }
}

extern "C" void kernel_launch(void* const* d_in, const int* in_sizes, int n_in,
                              void* d_out, int out_size, void* d_ws, size_t ws_size,
                              hipStream_t stream) {
    const float* x    = (const float*)d_in[0];
    const int*   eidx = (const int*)d_in[1];
    const float* W    = (const float*)d_in[2];
    const float* bias = (const float*)d_in[3];
    const float* eps  = (const float*)d_in[4];
    float*       out  = (float*)d_out;

    const size_t need = (size_t)BATCH * NNODE * CIN * sizeof(ushort);  // 8 MiB
    dim3 grid((BATCH * NNODE) / MB);   // 1024 blocks

    if (ws_size >= need) {
        ushort* xb = (ushort*)d_ws;
        const int nelem = BATCH * NNODE * CIN;                 // 4 M
        cvt_bf16<<<dim3(nelem / (256 * 8)), dim3(256), 0, stream>>>(x, xb);
        gin_fused<true><<<grid, dim3(THREADS), 0, stream>>>(x, xb, eidx, W, bias, eps, out);
    } else {
        gin_fused<false><<<grid, dim3(THREADS), 0, stream>>>(x, nullptr, eidx, W, bias, eps, out);
    }
}

// Round 3
// 95.038 us; speedup vs baseline: 1.7744x; 1.0035x over previous
//
#include <hip/hip_runtime.h>
#include <stdint.h>

// GINConv1d: B=4, N=8192, K=16, C_IN=C_OUT=128
#define BATCH   4
#define NNODE   8192
#define KNBR    16
#define CIN     128
#define COUT    128
#define MB      32          // rows (nodes) per block -> 1024 blocks
#define THREADS 256
#define HS_STRIDE 136       // shorts per h_s row: 128 + 8 pad -> 272B stride, uniform bank spread

typedef __attribute__((ext_vector_type(8))) short short8;   // 8 bf16 (MFMA A/B frag)
typedef __attribute__((ext_vector_type(4))) float f32x4;

__device__ __forceinline__ short bf16_rne(float f) {
    union { float f; uint32_t u; } v; v.f = f;
    return (short)((v.u + 0x7FFFu + ((v.u >> 16) & 1u)) >> 16);  // round-to-nearest-even
}
__device__ __forceinline__ float bf16_f32(short s) {
    union { uint32_t u; float f; } v; v.u = ((uint32_t)(uint16_t)s) << 16;
    return v.f;
}

// ---------------- prepass: x fp32 -> bf16 in workspace -----------------------------
__global__ __launch_bounds__(256)
void cvt_bf16(const float* __restrict__ x, ushort* __restrict__ xb) {
    const int gid = blockIdx.x * 256 + threadIdx.x;       // 8 elements per thread
    const f32x4* xp = (const f32x4*)x + (size_t)gid * 2;
    f32x4 a = xp[0], c = xp[1];
    short8 s;
    s[0]=bf16_rne(a[0]); s[1]=bf16_rne(a[1]); s[2]=bf16_rne(a[2]); s[3]=bf16_rne(a[3]);
    s[4]=bf16_rne(c[0]); s[5]=bf16_rne(c[1]); s[6]=bf16_rne(c[2]); s[7]=bf16_rne(c[3]);
    ((short8*)xb)[gid] = s;
}

// ---------------- fused gather + eps-residual + MFMA GEMM + bias + ReLU ------------
// launch_bounds(256,2): VGPR cap 256 so all 16 neighbor prefetches (128 data VGPRs)
// stay in flight -> Little's law concurrency, instead of the 56-VGPR load/add chain.
template<bool USEBF>
__global__ __launch_bounds__(THREADS, 2)
void gin_fused(const float*  __restrict__ x,      // [B,N,CIN] fp32
               const ushort* __restrict__ xb,     // [B,N,CIN] bf16 (if USEBF)
               const int*    __restrict__ eidx,   // [2,B,N,K] int32; plane 0 = source idx
               const float*  __restrict__ W,      // [COUT,CIN] fp32
               const float*  __restrict__ bias,   // [COUT] fp32
               const float*  __restrict__ epsp,   // [1] fp32
               float*        __restrict__ out)    // [B,N,COUT] fp32
{
    __shared__ __align__(16) short h_s[MB * HS_STRIDE];

    const int tid = threadIdx.x;
    // XCD-locality swizzle: blockIdx -> XCD round-robin (i & 7). Pin batch b to
    // XCDs {2b,2b+1} so each XCD's gather set = one batch (2 MiB bf16) -> L2-resident.
    const int i   = blockIdx.x;            // 0..1023
    const int xcd = i & 7;
    const int sub = i >> 3;                // 0..127
    const int b   = xcd >> 1;              // batch 0..3
    const int wbi = ((xcd & 1) << 7) | sub;// 0..255 within batch
    const int n0  = wbi * MB;
    const int row0 = b * NNODE + n0;

    const float eps1 = 1.0f + epsp[0];

    // ---------------- Phase A: gather + sum -> h_s (bf16) --------------------------
    {
        const int r  = tid >> 3;           // row within block, 0..31
        const int q  = tid & 7;            // channel slice, 16 ch each
        const int n  = n0 + r;
        const int c0 = q * 16;
        const int* ip = eidx + ((size_t)b * NNODE + n) * KNBR;   // plane 0

        int js[KNBR];
        #pragma unroll
        for (int p = 0; p < 4; ++p) {
            int4 jv = *(const int4*)(ip + p * 4);
            js[p*4+0]=jv.x; js[p*4+1]=jv.y; js[p*4+2]=jv.z; js[p*4+3]=jv.w;
        }

        float acc[16];

        if constexpr (USEBF) {
            const ushort* xbb = xb + (size_t)b * NNODE * CIN;
            const ushort* xs  = xbb + (size_t)n * CIN + c0;
            short8 s0 = *(const short8*)xs, s1 = *(const short8*)(xs + 8);

            // Prefetch ALL 16 neighbor slices into registers (32 x 16B loads in
            // flight per thread) BEFORE any accumulation -> memory-level parallelism.
            short8 t0[KNBR], t1[KNBR];
            #pragma unroll
            for (int k = 0; k < KNBR; ++k) {
                const ushort* xn = xbb + (size_t)js[k] * CIN + c0;
                t0[k] = *(const short8*)xn;
                t1[k] = *(const short8*)(xn + 8);
            }

            #pragma unroll
            for (int e = 0; e < 8; ++e) {
                acc[e]     = eps1 * bf16_f32(s0[e]);
                acc[8 + e] = eps1 * bf16_f32(s1[e]);
            }
            #pragma unroll
            for (int k = 0; k < KNBR; ++k) {
                #pragma unroll
                for (int e = 0; e < 8; ++e) {
                    acc[e]     += bf16_f32(t0[k][e]);
                    acc[8 + e] += bf16_f32(t1[k][e]);
                }
            }
        } else {
            const float* xbb = x + (size_t)b * NNODE * CIN;
            const float* xs  = xbb + (size_t)n * CIN + c0;
            #pragma unroll
            for (int p = 0; p < 4; ++p) {
                f32x4 v = *(const f32x4*)(xs + p * 4);
                acc[p*4+0]=eps1*v[0]; acc[p*4+1]=eps1*v[1]; acc[p*4+2]=eps1*v[2]; acc[p*4+3]=eps1*v[3];
            }
            #pragma unroll
            for (int k = 0; k < KNBR; ++k) {
                const float* xn = xbb + (size_t)js[k] * CIN + c0;
                #pragma unroll
                for (int p = 0; p < 4; ++p) {
                    f32x4 v = *(const f32x4*)(xn + p * 4);
                    acc[p*4+0]+=v[0]; acc[p*4+1]+=v[1]; acc[p*4+2]+=v[2]; acc[p*4+3]+=v[3];
                }
            }
        }

        short* hp = h_s + r * HS_STRIDE + c0;
        #pragma unroll
        for (int p = 0; p < 2; ++p) {
            short8 s;
            #pragma unroll
            for (int e = 0; e < 8; ++e) s[e] = bf16_rne(acc[p*8+e]);
            *(short8*)(hp + p * 8) = s;
        }
    }

    // ---------------- W -> bf16 B-fragments in registers (per-wave 32-out slice) ---
    const int wave = tid >> 6;
    const int lane = tid & 63;
    const int l16  = lane & 15;
    const int lq   = lane >> 4;            // quad 0..3

    short8 bfrag[2][4];                    // [o_tile][kb]: B[k][n]=W[o][c], n=l16, k=lq*8+j
    #pragma unroll
    for (int t = 0; t < 2; ++t) {
        const float* wp = W + (size_t)(wave * 32 + t * 16 + l16) * CIN;
        #pragma unroll
        for (int kb = 0; kb < 4; ++kb) {
            const float* wq = wp + kb * 32 + lq * 8;
            f32x4 f0 = *(const f32x4*)(wq);
            f32x4 f1 = *(const f32x4*)(wq + 4);
            short8 s;
            s[0]=bf16_rne(f0[0]); s[1]=bf16_rne(f0[1]); s[2]=bf16_rne(f0[2]); s[3]=bf16_rne(f0[3]);
            s[4]=bf16_rne(f1[0]); s[5]=bf16_rne(f1[1]); s[6]=bf16_rne(f1[2]); s[7]=bf16_rne(f1[3]);
            bfrag[t][kb] = s;
        }
    }
    const float bias0 = bias[wave * 32 + l16];
    const float bias1 = bias[wave * 32 + 16 + l16];

    __syncthreads();

    // ---------------- Phase B: MFMA GEMM + bias + ReLU -----------------------------
    float* outb = out + (size_t)row0 * COUT;
    #pragma unroll
    for (int rt = 0; rt < MB / 16; ++rt) {
        const short* ap = h_s + (rt * 16 + l16) * HS_STRIDE + lq * 8;
        short8 afrag[4];
        #pragma unroll
        for (int kb = 0; kb < 4; ++kb)
            afrag[kb] = *(const short8*)(ap + kb * 32);

        #pragma unroll
        for (int t = 0; t < 2; ++t) {
            f32x4 acc = { 0.f, 0.f, 0.f, 0.f };
            #pragma unroll
            for (int kb = 0; kb < 4; ++kb)
                acc = __builtin_amdgcn_mfma_f32_16x16x32_bf16(afrag[kb], bfrag[t][kb], acc, 0, 0, 0);

            const float bv  = t ? bias1 : bias0;
            const int   col = wave * 32 + t * 16 + l16;
            #pragma unroll
            for (int ii = 0; ii < 4; ++ii) {
                const int row = rt * 16 + lq * 4 + ii;   // C/D: row = quad*4 + reg
                float v = acc[ii] + bv;
                outb[(size_t)row * COUT + col] = v > 0.f ? v : 0.f;
            }
        }
    }
}

extern "C" void kernel_launch(void* const* d_in, const int* in_sizes, int n_in,
                              void* d_out, int out_size, void* d_ws, size_t ws_size,
                              hipStream_t stream) {
    const float* x    = (const float*)d_in[0];
    const int*   eidx = (const int*)d_in[1];
    const float* W    = (const float*)d_in[2];
    const float* bias = (const float*)d_in[3];
    const float* eps  = (const float*)d_in[4];
    float*       out  = (float*)d_out;

    const size_t need = (size_t)BATCH * NNODE * CIN * sizeof(ushort);  // 8 MiB
    dim3 grid((BATCH * NNODE) / MB);   // 1024 blocks

    if (ws_size >= need) {
        ushort* xb = (ushort*)d_ws;
        const int nelem = BATCH * NNODE * CIN;                 // 4 M
        cvt_bf16<<<dim3(nelem / (256 * 8)), dim3(256), 0, stream>>>(x, xb);
        gin_fused<true><<<grid, dim3(THREADS), 0, stream>>>(x, xb, eidx, W, bias, eps, out);
    } else {
        gin_fused<false><<<grid, dim3(THREADS), 0, stream>>>(x, nullptr, eidx, W, bias, eps, out);
    }
}